// Round 2
// baseline (972.022 us; speedup 1.0000x reference)
//
#include <hip/hip_runtime.h>

#define T_SEQ   2048
#define D_MODEL 1024
#define NHEAD   16
#define NEXP    8
#define HID_DIM 2048
#define NTOK    4096
#define MAXBLK  72
#define SLOTS   9216

#define BM 128
#define BN 128
#define BK 32
#define ASTR 40   // A LDS row stride (u16): 16B-aligned b128 reads, ~2-way banks
#define BSTR 34   // B^T LDS row stride (u16): 17 mod 32 -> full bank spread (4xb32 reads)

typedef unsigned short u16;
typedef unsigned int   u32;
typedef __bf16 bf16_t;
typedef bf16_t bf16x8 __attribute__((ext_vector_type(8)));
typedef float  f32x4  __attribute__((ext_vector_type(4)));
typedef u32    u32x4  __attribute__((ext_vector_type(4)));

__device__ __forceinline__ u16 f2bf_bits(float f) {
  u32 u = __builtin_bit_cast(u32, f);
  u += 0x7FFFu + ((u >> 16) & 1u);
  return (u16)(u >> 16);
}
__device__ __forceinline__ float bf2f(u16 s) {
  return __builtin_bit_cast(float, (u32)s << 16);
}
__device__ __forceinline__ bf16x8 frag_b128(const u16* p) {
  return *reinterpret_cast<const bf16x8*>(p);
}
__device__ __forceinline__ bf16x8 frag_4xb32(const u16* p) {
  union { u32x4 u; bf16x8 b; } c;
  c.u[0] = *reinterpret_cast<const u32*>(p);
  c.u[1] = *reinterpret_cast<const u32*>(p + 2);
  c.u[2] = *reinterpret_cast<const u32*>(p + 4);
  c.u[3] = *reinterpret_cast<const u32*>(p + 6);
  return c.b;
}
#define MFMA16(a,b,c) __builtin_amdgcn_mfma_f32_16x16x32_bf16((a),(b),(c),0,0,0)

// ---------------- rmsnorm (optionally split hi/lo bf16) ----------------
template<int SPLIT>
__global__ __launch_bounds__(256) void rmsnorm_kernel(
    const float* __restrict__ x, const float* __restrict__ w,
    u16* __restrict__ hi, u16* __restrict__ lo)
{
  int row = blockIdx.x, tid = threadIdx.x;
  const float* xr = x + (size_t)row * D_MODEL;
  f32x4 v = *reinterpret_cast<const f32x4*>(xr + tid * 4);
  float ss = v[0]*v[0] + v[1]*v[1] + v[2]*v[2] + v[3]*v[3];
#pragma unroll
  for (int off = 32; off >= 1; off >>= 1) ss += __shfl_xor(ss, off);
  __shared__ float part[4];
  if ((tid & 63) == 0) part[tid >> 6] = ss;
  __syncthreads();
  float rms = rsqrtf((part[0]+part[1]+part[2]+part[3]) * (1.0f/D_MODEL) + 1e-6f);
  f32x4 wv = *reinterpret_cast<const f32x4*>(w + tid * 4);
  u32 hw0=0, hw1=0, lw0=0, lw1=0;
#pragma unroll
  for (int j = 0; j < 4; ++j) {
    float f = v[j] * rms * wv[j];
    u16 hb = f2bf_bits(f);
    if (j < 2) hw0 |= (u32)hb << (16*j); else hw1 |= (u32)hb << (16*(j-2));
    if (SPLIT) {
      u16 lb = f2bf_bits(f - bf2f(hb));
      if (j < 2) lw0 |= (u32)lb << (16*j); else lw1 |= (u32)lb << (16*(j-2));
    }
  }
  u32* hp = reinterpret_cast<u32*>(hi + (size_t)row * D_MODEL + tid * 4);
  hp[0] = hw0; hp[1] = hw1;
  if (SPLIT) {
    u32* lp = reinterpret_cast<u32*>(lo + (size_t)row * D_MODEL + tid * 4);
    lp[0] = lw0; lp[1] = lw1;
  }
}

// ---------------- split-bf16 GEMM: C(f32) = (Ahi+Alo) @ B(f32), M=NTOK,N=K=1024 ----------------
__global__ __launch_bounds__(256, 2) void gemm_split_kernel(
    const u16* __restrict__ Ahi, const u16* __restrict__ Alo,
    const float* __restrict__ Bm, float* __restrict__ Cout)
{
  const int K = D_MODEL, N = D_MODEL;
  __shared__ __align__(16) u16 AhiS[BM*ASTR], AloS[BM*ASTR], BhiS[BN*BSTR], BloS[BN*BSTR];
  int tid = threadIdx.x, lane = tid & 63, wid = tid >> 6;
  int wm = wid >> 1, wn = wid & 1;
  int l15 = lane & 15, l4 = lane >> 4;
  size_t bm = (size_t)blockIdx.y * BM, bn = (size_t)blockIdx.x * BN;
  int ar = tid >> 2, ak = (tid & 3) * 8;
  int bk0 = tid >> 5, bc4 = (tid & 31) * 4;
  f32x4 acc[4][4] = {};
  for (int kt = 0; kt < K; kt += BK) {
    __syncthreads();
#pragma unroll
    for (int p = 0; p < 2; ++p) {
      int r = p*64 + ar;
      *reinterpret_cast<u32x4*>(&AhiS[r*ASTR + ak]) =
          *reinterpret_cast<const u32x4*>(Ahi + (bm + r)*K + kt + ak);
      *reinterpret_cast<u32x4*>(&AloS[r*ASTR + ak]) =
          *reinterpret_cast<const u32x4*>(Alo + (bm + r)*K + kt + ak);
    }
#pragma unroll
    for (int q = 0; q < 4; ++q) {
      int k = bk0 + q*8;
      f32x4 bv = *reinterpret_cast<const f32x4*>(Bm + (size_t)(kt + k)*N + bn + bc4);
#pragma unroll
      for (int j = 0; j < 4; ++j) {
        u16 hb = f2bf_bits(bv[j]);
        u16 lb = f2bf_bits(bv[j] - bf2f(hb));
        BhiS[(bc4 + j)*BSTR + k] = hb;
        BloS[(bc4 + j)*BSTR + k] = lb;
      }
    }
    __syncthreads();
    bf16x8 ahi[4], alo[4];
#pragma unroll
    for (int i = 0; i < 4; ++i) {
      ahi[i] = frag_b128(&AhiS[(wm*64 + i*16 + l15)*ASTR + l4*8]);
      alo[i] = frag_b128(&AloS[(wm*64 + i*16 + l15)*ASTR + l4*8]);
    }
#pragma unroll
    for (int ni = 0; ni < 4; ++ni) {
      bf16x8 bhi = frag_4xb32(&BhiS[(wn*64 + ni*16 + l15)*BSTR + l4*8]);
      bf16x8 blo = frag_4xb32(&BloS[(wn*64 + ni*16 + l15)*BSTR + l4*8]);
#pragma unroll
      for (int mi = 0; mi < 4; ++mi) {
        acc[mi][ni] = MFMA16(ahi[mi], bhi, acc[mi][ni]);
        acc[mi][ni] = MFMA16(ahi[mi], blo, acc[mi][ni]);
        acc[mi][ni] = MFMA16(alo[mi], bhi, acc[mi][ni]);
      }
    }
  }
#pragma unroll
  for (int mi = 0; mi < 4; ++mi)
#pragma unroll
    for (int ni = 0; ni < 4; ++ni)
#pragma unroll
      for (int r = 0; r < 4; ++r) {
        size_t row = bm + wm*64 + mi*16 + l4*4 + r;
        size_t col = bn + wn*64 + ni*16 + l15;
        Cout[row*N + col] = acc[mi][ni][r];
      }
}

// ---------------- WO GEMM: x2(f32) = resid + A(bf16) @ B(f32) ----------------
__global__ __launch_bounds__(256, 2) void gemm_wo_kernel(
    const u16* __restrict__ A, const float* __restrict__ Bm,
    const float* __restrict__ resid, float* __restrict__ Cout)
{
  const int K = D_MODEL, N = D_MODEL;
  __shared__ __align__(16) u16 As[BM*ASTR], Bs[BN*BSTR];
  int tid = threadIdx.x, lane = tid & 63, wid = tid >> 6;
  int wm = wid >> 1, wn = wid & 1;
  int l15 = lane & 15, l4 = lane >> 4;
  size_t bm = (size_t)blockIdx.y * BM, bn = (size_t)blockIdx.x * BN;
  int ar = tid >> 2, ak = (tid & 3) * 8;
  int bk0 = tid >> 5, bc4 = (tid & 31) * 4;
  f32x4 acc[4][4] = {};
  for (int kt = 0; kt < K; kt += BK) {
    __syncthreads();
#pragma unroll
    for (int p = 0; p < 2; ++p) {
      int r = p*64 + ar;
      *reinterpret_cast<u32x4*>(&As[r*ASTR + ak]) =
          *reinterpret_cast<const u32x4*>(A + (bm + r)*K + kt + ak);
    }
#pragma unroll
    for (int q = 0; q < 4; ++q) {
      int k = bk0 + q*8;
      f32x4 bv = *reinterpret_cast<const f32x4*>(Bm + (size_t)(kt + k)*N + bn + bc4);
#pragma unroll
      for (int j = 0; j < 4; ++j) Bs[(bc4 + j)*BSTR + k] = f2bf_bits(bv[j]);
    }
    __syncthreads();
    bf16x8 a[4];
#pragma unroll
    for (int i = 0; i < 4; ++i)
      a[i] = frag_b128(&As[(wm*64 + i*16 + l15)*ASTR + l4*8]);
#pragma unroll
    for (int ni = 0; ni < 4; ++ni) {
      bf16x8 b = frag_4xb32(&Bs[(wn*64 + ni*16 + l15)*BSTR + l4*8]);
#pragma unroll
      for (int mi = 0; mi < 4; ++mi)
        acc[mi][ni] = MFMA16(a[mi], b, acc[mi][ni]);
    }
  }
#pragma unroll
  for (int mi = 0; mi < 4; ++mi)
#pragma unroll
    for (int ni = 0; ni < 4; ++ni)
#pragma unroll
      for (int r = 0; r < 4; ++r) {
        size_t row = bm + wm*64 + mi*16 + l4*4 + r;
        size_t col = bn + wn*64 + ni*16 + l15;
        Cout[row*N + col] = resid[row*N + col] + acc[mi][ni][r];
      }
}

// ---------------- rope: f32 q/k/v -> hi/lo planes + bf16 v + f32 k/v outputs ----------------
__global__ __launch_bounds__(256) void rope_kernel(
    const float* __restrict__ qf, const float* __restrict__ kf, const float* __restrict__ vf,
    const float* __restrict__ freqs,
    u16* __restrict__ qhi, u16* __restrict__ qlo,
    u16* __restrict__ khi, u16* __restrict__ klo,
    u16* __restrict__ vbf, float* __restrict__ kout, float* __restrict__ vout)
{
  int i = blockIdx.x * 256 + threadIdx.x;   // NTOK*512 pairs
  int row = i >> 9, pr = i & 511;
  int hh = pr >> 5, p = pr & 31;
  int t = row & (T_SEQ - 1);
  size_t base = (size_t)row * D_MODEL + hh*64 + 2*p;
  float c = freqs[(size_t)(t*32 + p)*2];
  float s = freqs[(size_t)(t*32 + p)*2 + 1];
  float q0 = qf[base], q1 = qf[base+1];
  float k0 = kf[base], k1 = kf[base+1];
  float v0 = vf[base], v1 = vf[base+1];
  float qr0 = q0*c - q1*s, qr1 = q0*s + q1*c;
  float kr0 = k0*c - k1*s, kr1 = k0*s + k1*c;
  u16 h0 = f2bf_bits(qr0), h1 = f2bf_bits(qr1);
  qhi[base] = h0; qhi[base+1] = h1;
  qlo[base] = f2bf_bits(qr0 - bf2f(h0)); qlo[base+1] = f2bf_bits(qr1 - bf2f(h1));
  u16 kh0 = f2bf_bits(kr0), kh1 = f2bf_bits(kr1);
  khi[base] = kh0; khi[base+1] = kh1;
  klo[base] = f2bf_bits(kr0 - bf2f(kh0)); klo[base+1] = f2bf_bits(kr1 - bf2f(kh1));
  vbf[base] = f2bf_bits(v0); vbf[base+1] = f2bf_bits(v1);
  kout[base] = kr0; kout[base+1] = kr1;
  vout[base] = v0;  vout[base+1] = v1;
}

// ---------------- wg2[d][e] = sum_i wo[d][i]*ffnw[i]*gw[i][e] ----------------
__global__ __launch_bounds__(64) void wg2_kernel(
    const float* __restrict__ wo, const float* __restrict__ ffnw,
    const float* __restrict__ gw, float* __restrict__ wg2)
{
  int d = blockIdx.x, lane = threadIdx.x;
  const float* wr = wo + (size_t)d * D_MODEL;
  float acc[8] = {0,0,0,0,0,0,0,0};
#pragma unroll
  for (int i = 0; i < 4; ++i) {
    int c = lane*4 + i*256;
    f32x4 wv = *reinterpret_cast<const f32x4*>(wr + c);
    f32x4 fv = *reinterpret_cast<const f32x4*>(ffnw + c);
#pragma unroll
    for (int j = 0; j < 4; ++j) {
      float a = wv[j] * fv[j];
      f32x4 g0 = *reinterpret_cast<const f32x4*>(gw + (size_t)(c + j)*NEXP);
      f32x4 g1 = *reinterpret_cast<const f32x4*>(gw + (size_t)(c + j)*NEXP + 4);
      acc[0]+=a*g0[0]; acc[1]+=a*g0[1]; acc[2]+=a*g0[2]; acc[3]+=a*g0[3];
      acc[4]+=a*g1[0]; acc[5]+=a*g1[1]; acc[6]+=a*g1[2]; acc[7]+=a*g1[3];
    }
  }
#pragma unroll
  for (int off = 32; off >= 1; off >>= 1)
#pragma unroll
    for (int e = 0; e < 8; ++e) acc[e] += __shfl_xor(acc[e], off);
  if (lane == 0) {
#pragma unroll
    for (int e = 0; e < 8; ++e) wg2[(size_t)d*NEXP + e] = acc[e];
  }
}

// ---------------- Vg[t][h][e] = sum_{d in head h} v_f32[t][.]*wg2[.][e] ----------------
__global__ __launch_bounds__(256) void vg_kernel(
    const float* __restrict__ vf, const float* __restrict__ wg2, float* __restrict__ Vg)
{
  int tok = blockIdx.x * 4 + (threadIdx.x >> 6);
  int lane = threadIdx.x & 63;
  int hh = lane >> 2, part = lane & 3;
  const float* vr = vf + (size_t)tok * D_MODEL + hh*64 + part*16;
  const float* gr = wg2 + (size_t)(hh*64 + part*16) * NEXP;
  float acc[8] = {0,0,0,0,0,0,0,0};
#pragma unroll
  for (int i = 0; i < 4; ++i) {
    f32x4 vv = *reinterpret_cast<const f32x4*>(vr + i*4);
#pragma unroll
    for (int j = 0; j < 4; ++j) {
      float a = vv[j];
      f32x4 g0 = *reinterpret_cast<const f32x4*>(gr + (size_t)(i*4 + j)*NEXP);
      f32x4 g1 = *reinterpret_cast<const f32x4*>(gr + (size_t)(i*4 + j)*NEXP + 4);
      acc[0]+=a*g0[0]; acc[1]+=a*g0[1]; acc[2]+=a*g0[2]; acc[3]+=a*g0[3];
      acc[4]+=a*g1[0]; acc[5]+=a*g1[1]; acc[6]+=a*g1[2]; acc[7]+=a*g1[3];
    }
  }
#pragma unroll
  for (int off = 1; off < 4; off <<= 1)
#pragma unroll
    for (int e = 0; e < 8; ++e) acc[e] += __shfl_xor(acc[e], off);
  if (part == 0) {
#pragma unroll
    for (int e = 0; e < 8; ++e) Vg[((size_t)tok*NHEAD + hh)*NEXP + e] = acc[e];
  }
}

// ---------------- flash attention: split-bf16 scores, bf16 PV, fp32 gate projection ----------------
__global__ __launch_bounds__(256) void attn_kernel(
    const u16* __restrict__ Qhi, const u16* __restrict__ Qlo,
    const u16* __restrict__ Khi, const u16* __restrict__ Klo,
    const u16* __restrict__ Vb, const float* __restrict__ Vg,
    u16* __restrict__ Ob, float* __restrict__ raw_ao)
{
  int bh = blockIdx.x, b = bh >> 4, h = bh & 15;
  int qt = blockIdx.y;
  int tid = threadIdx.x, lane = tid & 63, wid = tid >> 6;
  int l15 = lane & 15, l4 = lane >> 4;

  __shared__ __align__(16) u16 VT[64][72];
  __shared__ __align__(16) u16 Pl[4][16][72];
  __shared__ float VgS[64][8];

  size_t qoff = ((size_t)(b*T_SEQ + qt*64 + wid*16)) * D_MODEL + h*64;
  bf16x8 qhiF[2], qloF[2];
#pragma unroll
  for (int s = 0; s < 2; ++s) {
    qhiF[s] = frag_b128(Qhi + qoff + (size_t)l15*D_MODEL + s*32 + l4*8);
    qloF[s] = frag_b128(Qlo + qoff + (size_t)l15*D_MODEL + s*32 + l4*8);
  }
  float m_r[4], l_r[4], racc[4][8];
  f32x4 oacc[4] = {};
#pragma unroll
  for (int r = 0; r < 4; ++r) {
    m_r[r] = -1e30f; l_r[r] = 0.f;
#pragma unroll
    for (int e = 0; e < 8; ++e) racc[r][e] = 0.f;
  }
  int vkey = tid >> 2, vd = (tid & 3) * 16;

  for (int kt = 0; kt <= qt; ++kt) {
    __syncthreads();
    {
      const u16* vsrc = Vb + ((size_t)(b*T_SEQ + kt*64 + vkey))*D_MODEL + h*64 + vd;
      union { u32x4 u[2]; u16 s[16]; } tv;
      tv.u[0] = *reinterpret_cast<const u32x4*>(vsrc);
      tv.u[1] = *reinterpret_cast<const u32x4*>(vsrc + 8);
#pragma unroll
      for (int j = 0; j < 16; ++j) VT[vd + j][vkey] = tv.s[j];
    }
    if (tid < 128) {
      int key = tid >> 1, eh = (tid & 1) * 4;
      const float* gsrc = Vg + ((size_t)(b*T_SEQ + kt*64 + key)*NHEAD + h)*NEXP + eh;
      *reinterpret_cast<f32x4*>(&VgS[key][eh]) = *reinterpret_cast<const f32x4*>(gsrc);
    }
    f32x4 sacc[4] = {};
    const u16* kbaseH = Khi + ((size_t)(b*T_SEQ + kt*64))*D_MODEL + h*64;
    const u16* kbaseL = Klo + ((size_t)(b*T_SEQ + kt*64))*D_MODEL + h*64;
#pragma unroll
    for (int n = 0; n < 4; ++n) {
#pragma unroll
      for (int s = 0; s < 2; ++s) {
        size_t koff = (size_t)(n*16 + l15)*D_MODEL + s*32 + l4*8;
        bf16x8 khiF = frag_b128(kbaseH + koff);
        bf16x8 kloF = frag_b128(kbaseL + koff);
        sacc[n] = MFMA16(qhiF[s], khiF, sacc[n]);
        sacc[n] = MFMA16(qhiF[s], kloF, sacc[n]);
        sacc[n] = MFMA16(qloF[s], khiF, sacc[n]);
      }
    }
    int q0 = qt*64 + wid*16 + l4*4;
    int k00 = kt*64 + l15;
#pragma unroll
    for (int n = 0; n < 4; ++n)
#pragma unroll
      for (int r = 0; r < 4; ++r) {
        float vv = sacc[n][r] * 0.125f;
        if (k00 + n*16 > q0 + r) vv = -1e30f;
        sacc[n][r] = vv;
      }
    float corr[4];
#pragma unroll
    for (int r = 0; r < 4; ++r) {
      float rm = fmaxf(fmaxf(sacc[0][r], sacc[1][r]), fmaxf(sacc[2][r], sacc[3][r]));
#pragma unroll
      for (int off = 1; off < 16; off <<= 1) rm = fmaxf(rm, __shfl_xor(rm, off));
      float mn = fmaxf(m_r[r], rm);
      corr[r] = __expf(m_r[r] - mn);
      m_r[r] = mn;
    }
#pragma unroll
    for (int r = 0; r < 4; ++r) {
      float rs = 0.f;
#pragma unroll
      for (int n = 0; n < 4; ++n) {
        float pp = __expf(sacc[n][r] - m_r[r]);
        sacc[n][r] = pp;
        rs += pp;
      }
#pragma unroll
      for (int off = 1; off < 16; off <<= 1) rs += __shfl_xor(rs, off);
      l_r[r] = l_r[r]*corr[r] + rs;
#pragma unroll
      for (int n2 = 0; n2 < 4; ++n2) oacc[n2][r] *= corr[r];
#pragma unroll
      for (int e = 0; e < 8; ++e) racc[r][e] *= corr[r];
    }
#pragma unroll
    for (int n = 0; n < 4; ++n)
#pragma unroll
      for (int r = 0; r < 4; ++r)
        Pl[wid][l4*4 + r][n*16 + l15] = f2bf_bits(sacc[n][r]);
    __syncthreads();
    // fp32 gate projection accumulate: racc += p * Vg (partial over keys == l15 mod 16)
#pragma unroll
    for (int n = 0; n < 4; ++n) {
      f32x4 g0 = *reinterpret_cast<const f32x4*>(&VgS[n*16 + l15][0]);
      f32x4 g1 = *reinterpret_cast<const f32x4*>(&VgS[n*16 + l15][4]);
#pragma unroll
      for (int r = 0; r < 4; ++r) {
        float pp = sacc[n][r];
        racc[r][0]+=pp*g0[0]; racc[r][1]+=pp*g0[1]; racc[r][2]+=pp*g0[2]; racc[r][3]+=pp*g0[3];
        racc[r][4]+=pp*g1[0]; racc[r][5]+=pp*g1[1]; racc[r][6]+=pp*g1[2]; racc[r][7]+=pp*g1[3];
      }
    }
#pragma unroll
    for (int s = 0; s < 2; ++s) {
      bf16x8 pa = frag_b128(&Pl[wid][l15][s*32 + l4*8]);
#pragma unroll
      for (int n = 0; n < 4; ++n) {
        bf16x8 vb8 = frag_b128(&VT[n*16 + l15][s*32 + l4*8]);
        oacc[n] = MFMA16(pa, vb8, oacc[n]);
      }
    }
  }
  float inv[4];
#pragma unroll
  for (int r = 0; r < 4; ++r) inv[r] = 1.0f / l_r[r];
  size_t obase = ((size_t)(b*T_SEQ + qt*64 + wid*16))*D_MODEL + h*64;
#pragma unroll
  for (int n = 0; n < 4; ++n)
#pragma unroll
    for (int r = 0; r < 4; ++r)
      Ob[obase + (size_t)(l4*4 + r)*D_MODEL + n*16 + l15] = f2bf_bits(oacc[n][r]*inv[r]);
  // FIX: racc held only keys == l15 (mod 16); reduce across the 16 l15-lanes.
#pragma unroll
  for (int off = 1; off < 16; off <<= 1)
#pragma unroll
    for (int r = 0; r < 4; ++r)
#pragma unroll
      for (int e = 0; e < 8; ++e)
        racc[r][e] += __shfl_xor(racc[r][e], off);
  if (l15 == 0) {
#pragma unroll
    for (int r = 0; r < 4; ++r) {
      size_t tokg = (size_t)(b*T_SEQ) + qt*64 + wid*16 + l4*4 + r;
#pragma unroll
      for (int e = 0; e < 8; ++e)
        raw_ao[(tokg*NHEAD + h)*NEXP + e] = racc[r][e]*inv[r];
    }
  }
}

// ---------------- gate: fp32 logits = rms * (x-part + attn-part), top-2 ----------------
__global__ void zero_counts_kernel(int* counts) {
  if (threadIdx.x < NEXP) counts[threadIdx.x] = 0;
}

__global__ __launch_bounds__(256) void gate2_kernel(
    const float* __restrict__ x, const float* __restrict__ x2,
    const float* __restrict__ ffnw, const float* __restrict__ gw,
    const float* __restrict__ raw_ao,
    int* __restrict__ gidx, float* __restrict__ gwt, int* __restrict__ counts)
{
  int tok = blockIdx.x * 4 + (threadIdx.x >> 6);
  int lane = threadIdx.x & 63;
  const float* xr = x + (size_t)tok * D_MODEL;
  const float* x2r = x2 + (size_t)tok * D_MODEL;
  float ss = 0.f;
  float lg[8] = {0,0,0,0,0,0,0,0};
#pragma unroll
  for (int i = 0; i < 4; ++i) {
    int d = lane*4 + i*256;
    f32x4 xv = *reinterpret_cast<const f32x4*>(xr + d);
    f32x4 x2v = *reinterpret_cast<const f32x4*>(x2r + d);
    f32x4 wv = *reinterpret_cast<const f32x4*>(ffnw + d);
    ss += x2v[0]*x2v[0] + x2v[1]*x2v[1] + x2v[2]*x2v[2] + x2v[3]*x2v[3];
#pragma unroll
    for (int j = 0; j < 4; ++j) {
      float a = xv[j]*wv[j];
      f32x4 g0 = *reinterpret_cast<const f32x4*>(gw + (size_t)(d + j)*NEXP);
      f32x4 g1 = *reinterpret_cast<const f32x4*>(gw + (size_t)(d + j)*NEXP + 4);
      lg[0]+=a*g0[0]; lg[1]+=a*g0[1]; lg[2]+=a*g0[2]; lg[3]+=a*g0[3];
      lg[4]+=a*g1[0]; lg[5]+=a*g1[1]; lg[6]+=a*g1[2]; lg[7]+=a*g1[3];
    }
  }
#pragma unroll
  for (int off = 1; off < 64; off <<= 1) {
    ss += __shfl_xor(ss, off);
#pragma unroll
    for (int e = 0; e < 8; ++e) lg[e] += __shfl_xor(lg[e], off);
  }
  float ah[8] = {0,0,0,0,0,0,0,0};
  if (lane < 16) {
    const float* ar = raw_ao + ((size_t)tok*NHEAD + lane)*NEXP;
#pragma unroll
    for (int e = 0; e < 8; ++e) ah[e] = ar[e];
  }
#pragma unroll
  for (int off = 1; off < 16; off <<= 1)
#pragma unroll
    for (int e = 0; e < 8; ++e) ah[e] += __shfl_xor(ah[e], off);
  if (lane == 0) {
    float rms = rsqrtf(ss*(1.0f/D_MODEL) + 1e-6f);
    float lo_[8], pp[8];
    float mx = -1e30f;
#pragma unroll
    for (int e = 0; e < 8; ++e) { lo_[e] = (lg[e] + ah[e]) * rms; mx = fmaxf(mx, lo_[e]); }
    float sum = 0.f;
#pragma unroll
    for (int e = 0; e < 8; ++e) { pp[e] = __expf(lo_[e] - mx); sum += pp[e]; }
    float isum = 1.0f/sum;
#pragma unroll
    for (int e = 0; e < 8; ++e) pp[e] *= isum;
    int i0 = 0;
    for (int e = 1; e < 8; ++e) if (pp[e] > pp[i0]) i0 = e;
    int i1 = (i0 == 0) ? 1 : 0;
    for (int e = 0; e < 8; ++e) if (e != i0 && pp[e] > pp[i1]) i1 = e;
    float v0 = pp[i0], v1 = pp[i1];
    float wnorm = 1.0f/(v0 + v1 + 1e-8f);
    gidx[2*tok] = i0; gidx[2*tok+1] = i1;
    gwt[2*tok] = v0*wnorm; gwt[2*tok+1] = v1*wnorm;
    atomicAdd(&counts[i0], 1); atomicAdd(&counts[i1], 1);
  }
}

// ---------------- routing: scan + scatter ----------------
__global__ __launch_bounds__(256) void scan_kernel(
    const int* __restrict__ counts, int* __restrict__ base, int* __restrict__ fill,
    int* __restrict__ blk_expert, int* __restrict__ perm_token)
{
  if (threadIdx.x == 0) {
    int b = 0, blk = 0;
    for (int e = 0; e < NEXP; ++e) {
      base[e] = b;
      fill[e] = 0;
      int nb = (counts[e] + 127) >> 7;
      for (int i = 0; i < nb; ++i) blk_expert[blk++] = e;
      b += nb << 7;
    }
    for (; blk < MAXBLK; ++blk) blk_expert[blk] = -1;
  }
  for (int i = threadIdx.x; i < SLOTS; i += 256) perm_token[i] = -1;
}

__global__ __launch_bounds__(256) void scatter_kernel(
    const int* __restrict__ gidx, const int* __restrict__ base, int* __restrict__ fill,
    int* __restrict__ perm_token, int* __restrict__ tok_slot)
{
  int t = blockIdx.x * 256 + threadIdx.x;
  if (t >= NTOK) return;
#pragma unroll
  for (int r = 0; r < 2; ++r) {
    int e = gidx[2*t + r];
    int pos = base[e] + atomicAdd(&fill[e], 1);
    perm_token[pos] = t;
    tok_slot[2*t + r] = pos;
  }
}

// ---------------- MoE GEMM1: t = silu(A@w1) * (A@w3), gathered rows ----------------
__global__ __launch_bounds__(256, 2) void moe_gemm1_kernel(
    const u16* __restrict__ Ah, const float* __restrict__ w1, const float* __restrict__ w3,
    const int* __restrict__ perm_token, const int* __restrict__ blk_expert,
    u16* __restrict__ tbuf)
{
  int mb = blockIdx.y;
  int e = blk_expert[mb];
  if (e < 0) return;
  __shared__ __align__(16) u16 As[BM*ASTR], B1s[BN*BSTR], B3s[BN*BSTR];
  int tid = threadIdx.x, lane = tid & 63, wid = tid >> 6;
  int wm = wid >> 1, wn = wid & 1;
  int l15 = lane & 15, l4 = lane >> 4;
  size_t bn = (size_t)blockIdx.x * BN;
  const float* w1e = w1 + (size_t)e * D_MODEL * HID_DIM;
  const float* w3e = w3 + (size_t)e * D_MODEL * HID_DIM;
  int ar = tid >> 2, ak = (tid & 3) * 8;
  int bk0 = tid >> 5, bc4 = (tid & 31) * 4;
  int tok0 = perm_token[mb*128 + ar];
  int tok1 = perm_token[mb*128 + 64 + ar];
  f32x4 acc1[4][4] = {}, acc3[4][4] = {};
  for (int kt = 0; kt < D_MODEL; kt += BK) {
    __syncthreads();
    {
      u32x4 av = {};
      if (tok0 >= 0) av = *reinterpret_cast<const u32x4*>(Ah + (size_t)tok0*D_MODEL + kt + ak);
      *reinterpret_cast<u32x4*>(&As[ar*ASTR + ak]) = av;
      u32x4 av2 = {};
      if (tok1 >= 0) av2 = *reinterpret_cast<const u32x4*>(Ah + (size_t)tok1*D_MODEL + kt + ak);
      *reinterpret_cast<u32x4*>(&As[(64 + ar)*ASTR + ak]) = av2;
    }
#pragma unroll
    for (int q = 0; q < 4; ++q) {
      int k = bk0 + q*8;
      f32x4 b1 = *reinterpret_cast<const f32x4*>(w1e + (size_t)(kt + k)*HID_DIM + bn + bc4);
      f32x4 b3 = *reinterpret_cast<const f32x4*>(w3e + (size_t)(kt + k)*HID_DIM + bn + bc4);
#pragma unroll
      for (int j = 0; j < 4; ++j) {
        B1s[(bc4 + j)*BSTR + k] = f2bf_bits(b1[j]);
        B3s[(bc4 + j)*BSTR + k] = f2bf_bits(b3[j]);
      }
    }
    __syncthreads();
    bf16x8 a[4];
#pragma unroll
    for (int i = 0; i < 4; ++i)
      a[i] = frag_b128(&As[(wm*64 + i*16 + l15)*ASTR + l4*8]);
#pragma unroll
    for (int ni = 0; ni < 4; ++ni) {
      bf16x8 b1f = frag_4xb32(&B1s[(wn*64 + ni*16 + l15)*BSTR + l4*8]);
#pragma unroll
      for (int mi = 0; mi < 4; ++mi)
        acc1[mi][ni] = MFMA16(a[mi], b1f, acc1[mi][ni]);
      bf16x8 b3f = frag_4xb32(&B3s[(wn*64 + ni*16 + l15)*BSTR + l4*8]);
#pragma unroll
      for (int mi = 0; mi < 4; ++mi)
        acc3[mi][ni] = MFMA16(a[mi], b3f, acc3[mi][ni]);
    }
  }
#pragma unroll
  for (int mi = 0; mi < 4; ++mi)
#pragma unroll
    for (int ni = 0; ni < 4; ++ni)
#pragma unroll
      for (int r = 0; r < 4; ++r) {
        size_t slot = (size_t)mb*128 + wm*64 + mi*16 + l4*4 + r;
        size_t col = bn + wn*64 + ni*16 + l15;
        float h1 = acc1[mi][ni][r], h3 = acc3[mi][ni][r];
        float sil = h1 / (1.0f + __expf(-h1));
        tbuf[slot*HID_DIM + col] = f2bf_bits(sil * h3);
      }
}

// ---------------- MoE GEMM2: y = t @ w2 ----------------
__global__ __launch_bounds__(256, 2) void moe_gemm2_kernel(
    const u16* __restrict__ tbuf, const float* __restrict__ w2,
    const int* __restrict__ blk_expert, u16* __restrict__ ybuf)
{
  int mb = blockIdx.y;
  int e = blk_expert[mb];
  if (e < 0) return;
  __shared__ __align__(16) u16 As[BM*ASTR], Bs[BN*BSTR];
  int tid = threadIdx.x, lane = tid & 63, wid = tid >> 6;
  int wm = wid >> 1, wn = wid & 1;
  int l15 = lane & 15, l4 = lane >> 4;
  size_t bm = (size_t)mb * BM, bn = (size_t)blockIdx.x * BN;
  const float* w2e = w2 + (size_t)e * HID_DIM * D_MODEL;
  int ar = tid >> 2, ak = (tid & 3) * 8;
  int bk0 = tid >> 5, bc4 = (tid & 31) * 4;
  f32x4 acc[4][4] = {};
  for (int kt = 0; kt < HID_DIM; kt += BK) {
    __syncthreads();
#pragma unroll
    for (int p = 0; p < 2; ++p) {
      int r = p*64 + ar;
      *reinterpret_cast<u32x4*>(&As[r*ASTR + ak]) =
          *reinterpret_cast<const u32x4*>(tbuf + (bm + r)*HID_DIM + kt + ak);
    }
#pragma unroll
    for (int q = 0; q < 4; ++q) {
      int k = bk0 + q*8;
      f32x4 bv = *reinterpret_cast<const f32x4*>(w2e + (size_t)(kt + k)*D_MODEL + bn + bc4);
#pragma unroll
      for (int j = 0; j < 4; ++j) Bs[(bc4 + j)*BSTR + k] = f2bf_bits(bv[j]);
    }
    __syncthreads();
    bf16x8 a[4];
#pragma unroll
    for (int i = 0; i < 4; ++i)
      a[i] = frag_b128(&As[(wm*64 + i*16 + l15)*ASTR + l4*8]);
#pragma unroll
    for (int ni = 0; ni < 4; ++ni) {
      bf16x8 b = frag_4xb32(&Bs[(wn*64 + ni*16 + l15)*BSTR + l4*8]);
#pragma unroll
      for (int mi = 0; mi < 4; ++mi)
        acc[mi][ni] = MFMA16(a[mi], b, acc[mi][ni]);
    }
  }
#pragma unroll
  for (int mi = 0; mi < 4; ++mi)
#pragma unroll
    for (int ni = 0; ni < 4; ++ni)
#pragma unroll
      for (int r = 0; r < 4; ++r) {
        size_t slot = bm + wm*64 + mi*16 + l4*4 + r;
        size_t col = bn + wn*64 + ni*16 + l15;
        ybuf[slot*D_MODEL + col] = f2bf_bits(acc[mi][ni][r]);
      }
}

// ---------------- combine: x_out = x2 + w0*y[s0] + w1*y[s1] ----------------
__global__ __launch_bounds__(256) void combine_kernel(
    const float* __restrict__ x2, const u16* __restrict__ ybuf,
    const int* __restrict__ tok_slot, const float* __restrict__ gwt,
    float* __restrict__ xout)
{
  int t = blockIdx.x;
  int c = threadIdx.x * 4;
  int s0 = tok_slot[2*t], s1 = tok_slot[2*t+1];
  float w0 = gwt[2*t], w1 = gwt[2*t+1];
  f32x4 xv = *reinterpret_cast<const f32x4*>(x2 + (size_t)t * D_MODEL + c);
  const u16* y0 = ybuf + (size_t)s0 * D_MODEL + c;
  const u16* y1 = ybuf + (size_t)s1 * D_MODEL + c;
  f32x4 o;
#pragma unroll
  for (int j = 0; j < 4; ++j)
    o[j] = xv[j] + w0 * bf2f(y0[j]) + w1 * bf2f(y1[j]);
  *reinterpret_cast<f32x4*>(xout + (size_t)t * D_MODEL + c) = o;
}

// ---------------- host launch ----------------
extern "C" void kernel_launch(void* const* d_in, const int* in_sizes, int n_in,
                              void* d_out, int out_size, void* d_ws, size_t ws_size,
                              hipStream_t stream)
{
  (void)in_sizes; (void)n_in; (void)out_size; (void)ws_size;
  const float* x     = (const float*)d_in[0];
  const float* freqs = (const float*)d_in[1];
  const float* attnw = (const float*)d_in[3];
  const float* ffnw  = (const float*)d_in[4];
  const float* wq    = (const float*)d_in[5];
  const float* wk    = (const float*)d_in[6];
  const float* wv    = (const float*)d_in[7];
  const float* wo    = (const float*)d_in[8];
  const float* gw    = (const float*)d_in[9];
  const float* w1    = (const float*)d_in[10];
  const float* w2    = (const float*)d_in[11];
  const float* w3    = (const float*)d_in[12];
  float* xout = (float*)d_out;
  float* kout = xout + (size_t)NTOK * D_MODEL;
  float* vout = kout + (size_t)NTOK * D_MODEL;

  const size_t PLANE = (size_t)NTOK * D_MODEL * 2;   // 8,388,608 B (bf16 plane)
  const size_t F32B  = (size_t)NTOK * D_MODEL * 4;   // 16,777,216 B
  char* p = (char*)d_ws;
  u16*   hhi = (u16*)p;                 p += PLANE;
  u16*   hlo = (u16*)p;                 p += PLANE;
  float* x2  = (float*)p;               p += F32B;
  u16*   hf  = (u16*)p;                 p += PLANE;
  char*  big = p;                       // phase1 region, phase2 aliases it
  float* qf32 = (float*)(big);
  float* kf32 = (float*)(big + F32B);
  float* vf32 = (float*)(big + 2*F32B);
  u16*   qhi  = (u16*)(big + 3*F32B);
  u16*   qlo  = (u16*)(big + 3*F32B + PLANE);
  u16*   khi  = (u16*)(big + 3*F32B + 2*PLANE);
  u16*   klo  = (u16*)(big + 3*F32B + 3*PLANE);
  u16*   vbf  = (u16*)(big + 3*F32B + 4*PLANE);
  u16*   aobf = (u16*)(big + 3*F32B + 5*PLANE);
  // phase2 aliases (q/k/v f32 + qhi dead by then):
  u16*   tbuf = (u16*)(big);                                     // SLOTS*HID*2 = 37,748,736
  u16*   ybuf = (u16*)(big + (size_t)SLOTS*HID_DIM*2);           // SLOTS*D*2   = 18,874,368
  p = big + 3*F32B + 6*PLANE;
  float* wg2    = (float*)p;  p += 1024*8*4;
  float* Vg     = (float*)p;  p += (size_t)NTOK*NHEAD*NEXP*4;
  float* raw_ao = (float*)p;  p += (size_t)NTOK*NHEAD*NEXP*4;
  int*   gidx   = (int*)p;    p += NTOK*2*4;
  float* gwt    = (float*)p;  p += NTOK*2*4;
  int*   tok_slot = (int*)p;  p += NTOK*2*4;
  int*   perm   = (int*)p;    p += SLOTS*4;
  int*   counts = (int*)p;    // + base[8], fill[8], blk_expert[MAXBLK]
  int*   base_  = counts + 8;
  int*   fill_  = counts + 16;
  int*   blk_e  = counts + 24;

  dim3 blk(256);
  // attention-branch precision path
  rmsnorm_kernel<1><<<NTOK, blk, 0, stream>>>(x, attnw, hhi, hlo);
  wg2_kernel<<<D_MODEL, 64, 0, stream>>>(wo, ffnw, gw, wg2);
  zero_counts_kernel<<<1, 64, 0, stream>>>(counts);
  dim3 g88(D_MODEL/BN, NTOK/BM);
  gemm_split_kernel<<<g88, blk, 0, stream>>>(hhi, hlo, wq, qf32);
  gemm_split_kernel<<<g88, blk, 0, stream>>>(hhi, hlo, wk, kf32);
  gemm_split_kernel<<<g88, blk, 0, stream>>>(hhi, hlo, wv, vf32);
  vg_kernel<<<NTOK/4, blk, 0, stream>>>(vf32, wg2, Vg);
  rope_kernel<<<(NTOK*512)/256, blk, 0, stream>>>(qf32, kf32, vf32, freqs,
                                                  qhi, qlo, khi, klo, vbf, kout, vout);
  dim3 ga(32, T_SEQ/64);
  attn_kernel<<<ga, blk, 0, stream>>>(qhi, qlo, khi, klo, vbf, Vg, aobf, raw_ao);
  gemm_wo_kernel<<<g88, blk, 0, stream>>>(aobf, wo, x, x2);
  // MoE
  rmsnorm_kernel<0><<<NTOK, blk, 0, stream>>>(x2, ffnw, hf, nullptr);
  gate2_kernel<<<NTOK/4, blk, 0, stream>>>(x, x2, ffnw, gw, raw_ao, gidx, gwt, counts);
  scan_kernel<<<1, blk, 0, stream>>>(counts, base_, fill_, blk_e, perm);
  scatter_kernel<<<NTOK/256, blk, 0, stream>>>(gidx, base_, fill_, perm, tok_slot);
  dim3 g1(HID_DIM/BN, MAXBLK);
  moe_gemm1_kernel<<<g1, blk, 0, stream>>>(hf, w1, w3, perm, blk_e, tbuf);
  dim3 g2(D_MODEL/BN, MAXBLK);
  moe_gemm2_kernel<<<g2, blk, 0, stream>>>(tbuf, w2, blk_e, ybuf);
  combine_kernel<<<NTOK, blk, 0, stream>>>(x2, ybuf, tok_slot, gwt, xout);
}